// Round 6
// baseline (548.670 us; speedup 1.0000x reference)
//
#include <hip/hip_runtime.h>
#include <hip/hip_bf16.h>

typedef unsigned short u16;
typedef __bf16 bf16x8 __attribute__((ext_vector_type(8)));
typedef float f32x4 __attribute__((ext_vector_type(4)));

#define DEVI __device__ __forceinline__

DEVI u16 f2bf(float f) {
    unsigned u = __builtin_bit_cast(unsigned, f);
    u += 0x7fff + ((u >> 16) & 1);   // RNE; inputs are finite
    return (u16)(u >> 16);
}
DEVI float bf2f(u16 h) {
    unsigned u = ((unsigned)h) << 16;
    return __builtin_bit_cast(float, u);
}

typedef __attribute__((address_space(1))) const unsigned GU32;
typedef __attribute__((address_space(3))) unsigned LU32;

DEVI void gload_lds16(const void* g, void* l) {
    __builtin_amdgcn_global_load_lds((GU32*)g, (LU32*)l, 16, 0, 0);
}

// Bijective XCD-chunk swizzle (m204).
DEVI int xcd_swz(int orig, int n) {
    int q = n >> 3, r = n & 7, x = orig & 7, o = orig >> 3;
    return (x < r ? x * (q + 1) : r * (q + 1) + (x - r) * q) + o;
}

// ===========================================================================
// 128x256 GEMM core, m201-style double-barrier phase schedule.
//   C[128x256] += A[MxK] * B^T  (B stored N x K row-major)
//   512 thr = 8 waves (2M x 4N); wave tile 64x64 = 4x4 frags of
//   mfma_f32_16x16x32_bf16 (acc = 64 regs/lane).
//   K consumed in kh-steps of 32. LDS = ring of 4 kh-slots, each
//   {A 128x32 (8KB) + B 256x32 (16KB)} = 96 KiB total.
//   Per kh phase: {8 ds_read; stage kh+3 (3 gloads); barrier(alpha);
//   lgkmcnt(0); setprio1; 16 MFMA; setprio0; counted vmcnt; barrier(beta)}.
//   vmcnt ladder 6/3/0 (3 gloads per slot, 3 slots in flight).
//   T2 XOR swizzle (inverse-swizzled global source + swizzled ds_read).
// ===========================================================================
DEVI void gemm_core(const u16* __restrict__ A, int lda,
                    const u16* __restrict__ B, int ldb,
                    int NK, int m0, int n0, u16* lds, f32x4 (&acc)[4][4])
{
    const int tid = threadIdx.x;
    const int wave = tid >> 6, lane = tid & 63;
    const int lr = lane & 15, lq = lane >> 4;
    const int wr = wave >> 2, wc = wave & 3;

    // Swizzled ds_read byte offsets (slot-relative). A at +0, B at +8192 B.
    int offA[4], offB[4];
    #pragma unroll
    for (int mi = 0; mi < 4; ++mi) {
        int ra = wr * 64 + mi * 16 + lr;
        offA[mi] = ra * 64 + ((lq * 16) ^ (((ra >> 1) & 3) << 4));
    }
    #pragma unroll
    for (int nj = 0; nj < 4; ++nj) {
        int rb = wc * 64 + nj * 16 + lr;
        offB[nj] = 8192 + rb * 64 + ((lq * 16) ^ (((rb >> 1) & 3) << 4));
    }

    // Staging: thread t covers row t>>2 (A and B-half0) and row 128+(t>>2)
    // (B-half1), 16B chunk (t&3), source column inverse-swizzled.
    const int rs = tid >> 2;
    const int cl = (tid & 3) ^ ((rs >> 1) & 3);       // logical 16B chunk
    const u16* pA  = A + (size_t)(m0 + rs) * lda + cl * 8;
    const u16* pB  = B + (size_t)(n0 + rs) * ldb + cl * 8;
    const u16* pB2 = B + (size_t)(n0 + 128 + rs) * ldb + cl * 8;
    const int dst = tid * 8;                          // u16 elems, wave-linear

#define STG(s) do {                                        \
        u16* b_ = lds + (s) * 12288;                       \
        gload_lds16(pA,  b_ + dst);                        \
        gload_lds16(pB,  b_ + 4096 + dst);                 \
        gload_lds16(pB2, b_ + 8192 + dst);                 \
        pA += 32; pB += 32; pB2 += 32;                     \
    } while (0)

    // Prologue: stage kh 0..2 (9 loads); confirm slot 0 (keep 6 newest).
    STG(0); STG(1); STG(2);
    asm volatile("s_waitcnt vmcnt(6)" ::: "memory");
    __builtin_amdgcn_s_barrier();

    for (int i = 0; i < NK; ++i) {
        const char* sb = (const char*)(lds + (i & 3) * 12288);
        bf16x8 af[4], bv[4];
        #pragma unroll
        for (int mi = 0; mi < 4; ++mi)
            af[mi] = *(const bf16x8*)(sb + offA[mi]);
        #pragma unroll
        for (int nj = 0; nj < 4; ++nj)
            bv[nj] = *(const bf16x8*)(sb + offB[nj]);
        // Stage kh i+3 into slot (i-1)&3: that slot's readers all drained
        // (lgkmcnt(0)) before barrier beta of kh i-1.
        if (i + 3 < NK) STG((i + 3) & 3);
        __builtin_amdgcn_sched_barrier(0);
        __builtin_amdgcn_s_barrier();                          // alpha
        asm volatile("s_waitcnt lgkmcnt(0)" ::: "memory");
        __builtin_amdgcn_sched_barrier(0);
        __builtin_amdgcn_s_setprio(1);
        #pragma unroll
        for (int mi = 0; mi < 4; ++mi)
            #pragma unroll
            for (int nj = 0; nj < 4; ++nj)
                acc[mi][nj] = __builtin_amdgcn_mfma_f32_16x16x32_bf16(
                    af[mi], bv[nj], acc[mi][nj], 0, 0, 0);
        __builtin_amdgcn_s_setprio(0);
        __builtin_amdgcn_sched_barrier(0);
        // Confirm slot i+1 before all waves cross beta.
        if (i < NK - 3)       { asm volatile("s_waitcnt vmcnt(6)" ::: "memory"); }
        else if (i == NK - 3) { asm volatile("s_waitcnt vmcnt(3)" ::: "memory"); }
        else if (i == NK - 2) { asm volatile("s_waitcnt vmcnt(0)" ::: "memory"); }
        __builtin_amdgcn_s_barrier();                          // beta
    }
#undef STG
}

// Output coords: row = m0 + wr*64 + mi*16 + lq*4 + rr, col = n0 + wc*64 + nj*16 + lr
#define EPI_COORDS()                                        \
    const int tid = threadIdx.x;                            \
    const int wave = tid >> 6, lane = tid & 63;             \
    const int lr = lane & 15, lq = lane >> 4;               \
    const int wr = wave >> 2, wc = wave & 3;                \
    (void)tid;

// ---------------------------------------------------------------------------
// Prep kernels
// ---------------------------------------------------------------------------
__global__ __launch_bounds__(256) void k_cast_x(const float* __restrict__ x, u16* __restrict__ xb)
{
    size_t i = (size_t)blockIdx.x * 256 + threadIdx.x;
    float4 f = ((const float4*)x)[i];
    ushort4 o;
    o.x = f2bf(f.x); o.y = f2bf(f.y); o.z = f2bf(f.z); o.w = f2bf(f.w);
    ((ushort4*)xb)[i] = o;
}

// in: R x C f32 row-major -> out: Cout x R bf16 row-major, zero-fill c >= C.
__global__ void k_transpose_w(const float* __restrict__ in, u16* __restrict__ out, int R, int C)
{
    __shared__ u16 t[32][33];
    int c0 = blockIdx.x * 32, r0 = blockIdx.y * 32;
    int tx = threadIdx.x, ty = threadIdx.y;
    #pragma unroll
    for (int p = 0; p < 4; ++p) {
        int rr = ty + p * 8;
        int c = c0 + tx;
        t[rr][tx] = (c < C) ? f2bf(in[(size_t)(r0 + rr) * C + c]) : (u16)0;
    }
    __syncthreads();
    #pragma unroll
    for (int p = 0; p < 4; ++p) {
        int cc = ty + p * 8;
        out[(size_t)(c0 + cc) * R + r0 + tx] = t[tx][cc];
    }
}

// ---------------------------------------------------------------------------
// GEMM1: h = x@Wi (raw acc, bf16) -> h[16384][3328]. Minimal epilogue.
// Grid: 1664 = 128 m-tiles x 13 n-tiles (m fast: consecutive share B panel).
// ---------------------------------------------------------------------------
__global__ __launch_bounds__(512, 2) void k_gemm1(
    const u16* __restrict__ xb, const u16* __restrict__ WibT, u16* __restrict__ h)
{
    __shared__ __align__(16) u16 lds[4 * 12288];
    f32x4 acc[4][4] = {};
    int L = xcd_swz(blockIdx.x, 1664);
    int m0 = (L % 128) * 128, n0 = (L / 128) * 256;
    gemm_core(xb, 768, WibT, 768, 24, m0, n0, lds, acc);

    EPI_COORDS();
    #pragma unroll
    for (int mi = 0; mi < 4; ++mi)
        #pragma unroll
        for (int nj = 0; nj < 4; ++nj)
            #pragma unroll
            for (int rr = 0; rr < 4; ++rr) {
                int m = m0 + wr * 64 + mi * 16 + lq * 4 + rr;
                int n = n0 + wc * 64 + nj * 16 + lr;
                h[(size_t)m * 3328 + n] = f2bf(acc[mi][nj][rr]);
            }
}

// ---------------------------------------------------------------------------
// Split pass: silu(h+bi) -> u in-place (cols 0..1535), vT (transposed),
// q/k (affine). Memory-bound. Grid (256, 50), 256 thr; 64x64 tile per block.
// ---------------------------------------------------------------------------
__global__ __launch_bounds__(256) void k_split(
    u16* __restrict__ h, const float* __restrict__ bi,
    const float* __restrict__ gq, const float* __restrict__ bq,
    const float* __restrict__ gk, const float* __restrict__ bk,
    u16* __restrict__ vT, u16* __restrict__ pq, u16* __restrict__ pk)
{
    const int m0 = blockIdx.x * 64, n0 = blockIdx.y * 64;
    const int tid = threadIdx.x;
    const int rrow = tid >> 2, c0 = (tid & 3) * 16;

    if (n0 < 1536) {                       // u region: in-place silu
        size_t base = (size_t)(m0 + rrow) * 3328 + n0 + c0;
        #pragma unroll
        for (int g = 0; g < 2; ++g) {
            bf16x8 hv = *(const bf16x8*)(h + base + g * 8);
            u16 ov[8];
            #pragma unroll
            for (int e = 0; e < 8; ++e) {
                float val = (float)hv[e] + bi[n0 + c0 + g * 8 + e];
                ov[e] = f2bf(val / (1.f + __expf(-val)));
            }
            *(uint4*)(h + base + g * 8) = *(const uint4*)ov;
        }
    } else if (n0 < 3072) {                // v region: silu + transpose -> vT
        __shared__ u16 t[64][72];
        size_t base = (size_t)(m0 + rrow) * 3328 + n0 + c0;
        #pragma unroll
        for (int g = 0; g < 2; ++g) {
            bf16x8 hv = *(const bf16x8*)(h + base + g * 8);
            #pragma unroll
            for (int e = 0; e < 8; ++e) {
                float val = (float)hv[e] + bi[n0 + c0 + g * 8 + e];
                t[rrow][c0 + g * 8 + e] = f2bf(val / (1.f + __expf(-val)));
            }
        }
        __syncthreads();
        const int b = m0 >> 12, mm = m0 & 4095, d0 = n0 - 1536;
        #pragma unroll
        for (int p = 0; p < 2; ++p) {
            int dr = (tid >> 3) + p * 32;
            int nc = (tid & 7) * 8;
            u16 tmp[8];
            #pragma unroll
            for (int e = 0; e < 8; ++e) tmp[e] = t[nc + e][dr];
            *(uint4*)(vT + (size_t)b * 1536 * 4096 + (size_t)(d0 + dr) * 4096 + mm + nc) = *(const uint4*)tmp;
        }
    } else {                               // qk region: silu + affine
        size_t base = (size_t)(m0 + rrow) * 3328 + n0 + c0;
        int cb = n0 + c0 - 3072;
        u16 qv[16], kv[16];
        #pragma unroll
        for (int g = 0; g < 2; ++g) {
            bf16x8 hv = *(const bf16x8*)(h + base + g * 8);
            #pragma unroll
            for (int e = 0; e < 8; ++e) {
                int c = cb + g * 8 + e;
                float val = (float)hv[e] + bi[3072 + c];
                float s = val / (1.f + __expf(-val));
                qv[g * 8 + e] = f2bf(s * gq[c] + bq[c]);
                kv[g * 8 + e] = f2bf(s * gk[c] + bk[c]);
            }
        }
        size_t ob = (size_t)(m0 + rrow) * 128 + cb;
        *(uint4*)(pq + ob)     = *(const uint4*)qv;
        *(uint4*)(pq + ob + 8) = *(const uint4*)(qv + 8);
        *(uint4*)(pk + ob)     = *(const uint4*)kv;
        *(uint4*)(pk + ob + 8) = *(const uint4*)(kv + 8);
    }
}

// ---------------------------------------------------------------------------
// Scores: P = relu(q@k^T / sqrt(128))^2 / 4096, 2-batch chunk, bf16 out.
// Grid (512, 2): 32 m-tiles x 16 n-tiles per batch.
// ---------------------------------------------------------------------------
__global__ __launch_bounds__(512, 2) void k_scores(
    const u16* __restrict__ q, const u16* __restrict__ k, u16* __restrict__ P, int b0)
{
    __shared__ __align__(16) u16 lds[4 * 12288];
    f32x4 acc[4][4] = {};
    int bb = blockIdx.y;
    int b  = b0 + bb;
    const u16* A = q + (size_t)b * 4096 * 128;
    const u16* B = k + (size_t)b * 4096 * 128;
    int L = xcd_swz(blockIdx.x, 512);
    int m0 = (L % 32) * 128, n0 = (L / 32) * 256;
    gemm_core(A, 128, B, 128, 4, m0, n0, lds, acc);

    u16* Pb = P + (size_t)bb * 4096 * 4096;
    const float sc = 1.f / (128.f * 4096.f);
    EPI_COORDS();
    #pragma unroll
    for (int mi = 0; mi < 4; ++mi)
        #pragma unroll
        for (int nj = 0; nj < 4; ++nj)
            #pragma unroll
            for (int rr = 0; rr < 4; ++rr) {
                int m = m0 + wr * 64 + mi * 16 + lq * 4 + rr;
                int n = n0 + wc * 64 + nj * 16 + lr;
                float a = fmaxf(acc[mi][nj][rr], 0.f);
                Pb[(size_t)m * 4096 + n] = f2bf(a * a * sc);
            }
}

// ---------------------------------------------------------------------------
// PV: z = P @ v (B = vT); epilogue uz = u * z in place over h's u-region.
// Grid (192, 2): 32 m-tiles x 6 n-tiles per batch.
// ---------------------------------------------------------------------------
__global__ __launch_bounds__(512, 2) void k_zu(
    const u16* __restrict__ P, const u16* __restrict__ vT, u16* __restrict__ h, int b0)
{
    __shared__ __align__(16) u16 lds[4 * 12288];
    f32x4 acc[4][4] = {};
    int bb = blockIdx.y;
    int b  = b0 + bb;
    const u16* A = P  + (size_t)bb * 4096 * 4096;   // 4096 x 4096
    const u16* B = vT + (size_t)b * 1536 * 4096;    // 1536 x 4096 (N x K)
    int L = xcd_swz(blockIdx.x, 192);
    int m0 = (L % 32) * 128, n0 = (L / 32) * 256;
    gemm_core(A, 4096, B, 4096, 128, m0, n0, lds, acc);

    EPI_COORDS();
    #pragma unroll
    for (int mi = 0; mi < 4; ++mi)
        #pragma unroll
        for (int nj = 0; nj < 4; ++nj)
            #pragma unroll
            for (int rr = 0; rr < 4; ++rr) {
                int m = m0 + wr * 64 + mi * 16 + lq * 4 + rr;
                int n = n0 + wc * 64 + nj * 16 + lr;
                size_t idx = (size_t)(b * 4096 + m) * 3328 + n;
                h[idx] = f2bf(bf2f(h[idx]) * acc[mi][nj][rr]);
            }
}

// ---------------------------------------------------------------------------
// GEMM3: o = (u*z) @ Wo + bo -> f32 out  (A = h's u-region, lda 3328)
// Grid 384 = 128 m-tiles x 3 n-tiles.
// ---------------------------------------------------------------------------
__global__ __launch_bounds__(512, 2) void k_out(
    const u16* __restrict__ h, const u16* __restrict__ WobT,
    const float* __restrict__ bo, float* __restrict__ out)
{
    __shared__ __align__(16) u16 lds[4 * 12288];
    f32x4 acc[4][4] = {};
    int L = xcd_swz(blockIdx.x, 384);
    int m0 = (L % 128) * 128, n0 = (L / 128) * 256;
    gemm_core(h, 3328, WobT, 1536, 48, m0, n0, lds, acc);

    EPI_COORDS();
    #pragma unroll
    for (int mi = 0; mi < 4; ++mi)
        #pragma unroll
        for (int nj = 0; nj < 4; ++nj)
            #pragma unroll
            for (int rr = 0; rr < 4; ++rr) {
                int m = m0 + wr * 64 + mi * 16 + lq * 4 + rr;
                int n = n0 + wc * 64 + nj * 16 + lr;
                out[(size_t)m * 768 + n] = acc[mi][nj][rr] + bo[n];
            }
}

// ---------------------------------------------------------------------------
extern "C" void kernel_launch(void* const* d_in, const int* in_sizes, int n_in,
                              void* d_out, int out_size, void* d_ws, size_t ws_size,
                              hipStream_t stream)
{
    const float* x  = (const float*)d_in[0];
    const float* Wi = (const float*)d_in[1];
    const float* bi = (const float*)d_in[2];
    const float* gq = (const float*)d_in[3];
    const float* bq = (const float*)d_in[4];
    const float* gk = (const float*)d_in[5];
    const float* bk = (const float*)d_in[6];
    const float* Wo = (const float*)d_in[7];
    const float* bo = (const float*)d_in[8];
    float* out = (float*)d_out;

    char* ws = (char*)d_ws;
    size_t off = 0;
    auto alloc = [&](size_t bytes) -> void* {
        void* p = ws + off;
        off += (bytes + 255) & ~(size_t)255;
        return p;
    };
    u16* xb   = (u16*)alloc((size_t)16384 * 768 * 2);
    u16* WibT = (u16*)alloc((size_t)3328 * 768 * 2);     // padded N: 3200 -> 3328
    u16* WobT = (u16*)alloc((size_t)768 * 1536 * 2);
    u16* h    = (u16*)alloc((size_t)16384 * 3328 * 2);   // raw GEMM1 out; u/uz in place
    u16* vT   = (u16*)alloc((size_t)4 * 1536 * 4096 * 2);
    u16* q    = (u16*)alloc((size_t)16384 * 128 * 2);
    u16* k    = (u16*)alloc((size_t)16384 * 128 * 2);
    u16* P    = (u16*)alloc((size_t)2 * 4096 * 4096 * 2); // 2-batch chunk (ws-safe)

    k_cast_x<<<dim3(12288), dim3(256), 0, stream>>>(x, xb);
    k_transpose_w<<<dim3(3328 / 32, 768 / 32), dim3(32, 8), 0, stream>>>(Wi, WibT, 768, 3200);
    k_transpose_w<<<dim3(768 / 32, 1536 / 32), dim3(32, 8), 0, stream>>>(Wo, WobT, 1536, 768);

    k_gemm1<<<dim3(1664), dim3(512), 0, stream>>>(xb, WibT, h);
    k_split<<<dim3(256, 50), dim3(256), 0, stream>>>(h, bi, gq, bq, gk, bk, vT, q, k);

    for (int b0 = 0; b0 < 4; b0 += 2) {
        k_scores<<<dim3(512, 2), dim3(512), 0, stream>>>(q, k, P, b0);
        k_zu<<<dim3(192, 2), dim3(512), 0, stream>>>(P, vT, h, b0);
    }

    k_out<<<dim3(384), dim3(512), 0, stream>>>(h, WobT, bo, out);
}

// Round 8
// 498.298 us; speedup vs baseline: 1.1011x; 1.1011x over previous
//
#include <hip/hip_runtime.h>
#include <hip/hip_bf16.h>

typedef unsigned short u16;
typedef __bf16 bf16x8 __attribute__((ext_vector_type(8)));
typedef float f32x4 __attribute__((ext_vector_type(4)));

#define DEVI __device__ __forceinline__

DEVI u16 f2bf(float f) {
    unsigned u = __builtin_bit_cast(unsigned, f);
    u += 0x7fff + ((u >> 16) & 1);   // RNE; inputs are finite
    return (u16)(u >> 16);
}
DEVI float bf2f(u16 h) {
    unsigned u = ((unsigned)h) << 16;
    return __builtin_bit_cast(float, u);
}

typedef __attribute__((address_space(1))) const unsigned GU32;
typedef __attribute__((address_space(3))) unsigned LU32;

DEVI void gload_lds16(const void* g, void* l) {
    __builtin_amdgcn_global_load_lds((GU32*)g, (LU32*)l, 16, 0, 0);
}

// Bijective XCD-chunk swizzle (m204).
DEVI int xcd_swz(int orig, int n) {
    int q = n >> 3, r = n & 7, x = orig & 7, o = orig >> 3;
    return (x < r ? x * (q + 1) : r * (q + 1) + (x - r) * q) + o;
}

// ===========================================================================
// 128x256 GEMM core: ring-3 of BK=32 slots, 72 KiB LDS -> 2 blocks/CU (TLP).
//   C[128x256] += A[MxK] * B^T  (B stored N x K row-major)
//   512 thr = 8 waves (2M x 4N); wave tile 64x64 = 4x4 frags of
//   mfma_f32_16x16x32_bf16.
//   Slot = {A 128x32 (8KB) + B 256x32 (16KB)} = 24KB; 3 slots = 72KB.
//   Per iter i: [ds_read slot i%3] [stage slot (i+2)%3 : 3 gloads]
//               [16 MFMA, setprio] [vmcnt(3): drain slot i+1, keep i+2]
//               [s_barrier + sched_barrier].
//   ORDERING INVARIANT (R7 bug fix): vmcnt BEFORE the barrier; reads AFTER
//   the previous barrier -> every wave drained its own staging loads for a
//   slot before any wave reads it. WAR: slot (i+2)%3 == slot (i-1)%3, whose
//   readers all finished before the barrier at end of iter i-1; the stage is
//   issued after that barrier.
//   T2 XOR swizzle (inverse-swizzled global source + swizzled ds_read).
// ===========================================================================
DEVI void gemm_core(const u16* __restrict__ A, int lda,
                    const u16* __restrict__ B, int ldb,
                    int NK, int m0, int n0, u16* lds, f32x4 (&acc)[4][4])
{
    const int tid = threadIdx.x;
    const int wave = tid >> 6, lane = tid & 63;
    const int lr = lane & 15, lq = lane >> 4;
    const int wr = wave >> 2, wc = wave & 3;

    // Swizzled ds_read byte offsets (slot-relative). A at +0, B at +8192 B.
    int offA[4], offB[4];
    #pragma unroll
    for (int mi = 0; mi < 4; ++mi) {
        int ra = wr * 64 + mi * 16 + lr;
        offA[mi] = ra * 64 + ((lq * 16) ^ (((ra >> 1) & 3) << 4));
    }
    #pragma unroll
    for (int nj = 0; nj < 4; ++nj) {
        int rb = wc * 64 + nj * 16 + lr;
        offB[nj] = 8192 + rb * 64 + ((lq * 16) ^ (((rb >> 1) & 3) << 4));
    }

    // Staging: thread t covers row t>>2 (A and B rows 0..127) and row
    // 128+(t>>2) (B rows 128..255), 16B chunk (t&3); source column
    // inverse-swizzled ((r>>1)&3 == (t>>3)&3, invariant under r+=128).
    const int rs = tid >> 2;
    const int cl = (tid & 3) ^ ((tid >> 3) & 3);
    const u16* pA  = A + (size_t)(m0 + rs) * lda + cl * 8;
    const u16* pB  = B + (size_t)(n0 + rs) * ldb + cl * 8;
    const u16* pB2 = pB + (size_t)128 * ldb;
    const int t8 = tid * 8;

#define STG(s) do {                                        \
        u16* b_ = lds + (s) * 12288;                       \
        gload_lds16(pA,  b_ + t8);                         \
        gload_lds16(pB,  b_ + 4096 + t8);                  \
        gload_lds16(pB2, b_ + 8192 + t8);                  \
        pA += 32; pB += 32; pB2 += 32;                     \
    } while (0)

    // Prologue: stage slots 0,1; drain slot 0 (keep slot 1's 3 in flight).
    STG(0); STG(1);
    asm volatile("s_waitcnt vmcnt(3)" ::: "memory");
    __builtin_amdgcn_s_barrier();
    __builtin_amdgcn_sched_barrier(0);

    int sl = 0;
    for (int i = 0; i < NK; ++i) {
        const char* sb = (const char*)(lds + sl * 12288);
        bf16x8 af[4], bv[4];
        #pragma unroll
        for (int mi = 0; mi < 4; ++mi)
            af[mi] = *(const bf16x8*)(sb + offA[mi]);
        #pragma unroll
        for (int nj = 0; nj < 4; ++nj)
            bv[nj] = *(const bf16x8*)(sb + offB[nj]);

        int s2 = sl + 2; if (s2 >= 3) s2 -= 3;
        if (i + 2 < NK) STG(s2);

        __builtin_amdgcn_s_setprio(1);
        #pragma unroll
        for (int mi = 0; mi < 4; ++mi)
            #pragma unroll
            for (int nj = 0; nj < 4; ++nj)
                acc[mi][nj] = __builtin_amdgcn_mfma_f32_16x16x32_bf16(
                    af[mi], bv[nj], acc[mi][nj], 0, 0, 0);
        __builtin_amdgcn_s_setprio(0);

        if (i + 1 < NK) {
            // Drain slot i+1's loads (own), THEN barrier -> slot i+1
            // globally visible for next iter's reads.
            if (i + 2 < NK) { asm volatile("s_waitcnt vmcnt(3)" ::: "memory"); }
            else            { asm volatile("s_waitcnt vmcnt(0)" ::: "memory"); }
            __builtin_amdgcn_s_barrier();
            __builtin_amdgcn_sched_barrier(0);
        }
        sl = (sl == 2) ? 0 : sl + 1;
    }
#undef STG
}

// Output coords: row = m0 + wr*64 + mi*16 + lq*4 + rr, col = n0 + wc*64 + nj*16 + lr
#define EPI_COORDS()                                        \
    const int tid = threadIdx.x;                            \
    const int wave = tid >> 6, lane = tid & 63;             \
    const int lr = lane & 15, lq = lane >> 4;               \
    const int wr = wave >> 2, wc = wave & 3;                \
    (void)tid;

// ---------------------------------------------------------------------------
// Prep kernels
// ---------------------------------------------------------------------------
__global__ __launch_bounds__(256) void k_cast_x(const float* __restrict__ x, u16* __restrict__ xb)
{
    size_t i = (size_t)blockIdx.x * 256 + threadIdx.x;
    float4 f = ((const float4*)x)[i];
    ushort4 o;
    o.x = f2bf(f.x); o.y = f2bf(f.y); o.z = f2bf(f.z); o.w = f2bf(f.w);
    ((ushort4*)xb)[i] = o;
}

// in: R x C f32 row-major -> out: Cout x R bf16 row-major, zero-fill c >= C.
__global__ void k_transpose_w(const float* __restrict__ in, u16* __restrict__ out, int R, int C)
{
    __shared__ u16 t[32][33];
    int c0 = blockIdx.x * 32, r0 = blockIdx.y * 32;
    int tx = threadIdx.x, ty = threadIdx.y;
    #pragma unroll
    for (int p = 0; p < 4; ++p) {
        int rr = ty + p * 8;
        int c = c0 + tx;
        t[rr][tx] = (c < C) ? f2bf(in[(size_t)(r0 + rr) * C + c]) : (u16)0;
    }
    __syncthreads();
    #pragma unroll
    for (int p = 0; p < 4; ++p) {
        int cc = ty + p * 8;
        out[(size_t)(c0 + cc) * R + r0 + tx] = t[tx][cc];
    }
}

// ---------------------------------------------------------------------------
// GEMM1: h = x@Wi (raw acc, bf16) -> h[16384][3328]. Minimal epilogue.
// Grid: 1664 = 128 m-tiles x 13 n-tiles (m fast: same-XCD blocks share B).
// ---------------------------------------------------------------------------
__global__ __launch_bounds__(512, 4) void k_gemm1(
    const u16* __restrict__ xb, const u16* __restrict__ WibT, u16* __restrict__ h)
{
    __shared__ __align__(16) u16 lds[3 * 12288];
    f32x4 acc[4][4] = {};
    int L = xcd_swz(blockIdx.x, 1664);
    int m0 = (L % 128) * 128, n0 = (L / 128) * 256;
    gemm_core(xb, 768, WibT, 768, 24, m0, n0, lds, acc);

    EPI_COORDS();
    #pragma unroll
    for (int mi = 0; mi < 4; ++mi)
        #pragma unroll
        for (int nj = 0; nj < 4; ++nj)
            #pragma unroll
            for (int rr = 0; rr < 4; ++rr) {
                int m = m0 + wr * 64 + mi * 16 + lq * 4 + rr;
                int n = n0 + wc * 64 + nj * 16 + lr;
                h[(size_t)m * 3328 + n] = f2bf(acc[mi][nj][rr]);
            }
}

// ---------------------------------------------------------------------------
// Split pass: silu(h+bi) -> u in-place (cols 0..1535), vT (transposed),
// q/k (affine). Memory-bound. Grid (256, 50), 256 thr; 64x64 tile per block.
// ---------------------------------------------------------------------------
__global__ __launch_bounds__(256) void k_split(
    u16* __restrict__ h, const float* __restrict__ bi,
    const float* __restrict__ gq, const float* __restrict__ bq,
    const float* __restrict__ gk, const float* __restrict__ bk,
    u16* __restrict__ vT, u16* __restrict__ pq, u16* __restrict__ pk)
{
    const int m0 = blockIdx.x * 64, n0 = blockIdx.y * 64;
    const int tid = threadIdx.x;
    const int rrow = tid >> 2, c0 = (tid & 3) * 16;

    if (n0 < 1536) {                       // u region: in-place silu
        size_t base = (size_t)(m0 + rrow) * 3328 + n0 + c0;
        #pragma unroll
        for (int g = 0; g < 2; ++g) {
            bf16x8 hv = *(const bf16x8*)(h + base + g * 8);
            u16 ov[8];
            #pragma unroll
            for (int e = 0; e < 8; ++e) {
                float val = (float)hv[e] + bi[n0 + c0 + g * 8 + e];
                ov[e] = f2bf(val / (1.f + __expf(-val)));
            }
            *(uint4*)(h + base + g * 8) = *(const uint4*)ov;
        }
    } else if (n0 < 3072) {                // v region: silu + transpose -> vT
        __shared__ u16 t[64][72];
        size_t base = (size_t)(m0 + rrow) * 3328 + n0 + c0;
        #pragma unroll
        for (int g = 0; g < 2; ++g) {
            bf16x8 hv = *(const bf16x8*)(h + base + g * 8);
            #pragma unroll
            for (int e = 0; e < 8; ++e) {
                float val = (float)hv[e] + bi[n0 + c0 + g * 8 + e];
                t[rrow][c0 + g * 8 + e] = f2bf(val / (1.f + __expf(-val)));
            }
        }
        __syncthreads();
        const int b = m0 >> 12, mm = m0 & 4095, d0 = n0 - 1536;
        #pragma unroll
        for (int p = 0; p < 2; ++p) {
            int dr = (tid >> 3) + p * 32;
            int nc = (tid & 7) * 8;
            u16 tmp[8];
            #pragma unroll
            for (int e = 0; e < 8; ++e) tmp[e] = t[nc + e][dr];
            *(uint4*)(vT + (size_t)b * 1536 * 4096 + (size_t)(d0 + dr) * 4096 + mm + nc) = *(const uint4*)tmp;
        }
    } else {                               // qk region: silu + affine
        size_t base = (size_t)(m0 + rrow) * 3328 + n0 + c0;
        int cb = n0 + c0 - 3072;
        u16 qv[16], kv[16];
        #pragma unroll
        for (int g = 0; g < 2; ++g) {
            bf16x8 hv = *(const bf16x8*)(h + base + g * 8);
            #pragma unroll
            for (int e = 0; e < 8; ++e) {
                int c = cb + g * 8 + e;
                float val = (float)hv[e] + bi[3072 + c];
                float s = val / (1.f + __expf(-val));
                qv[g * 8 + e] = f2bf(s * gq[c] + bq[c]);
                kv[g * 8 + e] = f2bf(s * gk[c] + bk[c]);
            }
        }
        size_t ob = (size_t)(m0 + rrow) * 128 + cb;
        *(uint4*)(pq + ob)     = *(const uint4*)qv;
        *(uint4*)(pq + ob + 8) = *(const uint4*)(qv + 8);
        *(uint4*)(pk + ob)     = *(const uint4*)kv;
        *(uint4*)(pk + ob + 8) = *(const uint4*)(kv + 8);
    }
}

// ---------------------------------------------------------------------------
// Scores: P = relu(q@k^T / sqrt(128))^2 / 4096, 2-batch chunk, bf16 out.
// Grid (512, 2): 32 m-tiles x 16 n-tiles per batch.
// ---------------------------------------------------------------------------
__global__ __launch_bounds__(512, 4) void k_scores(
    const u16* __restrict__ q, const u16* __restrict__ k, u16* __restrict__ P, int b0)
{
    __shared__ __align__(16) u16 lds[3 * 12288];
    f32x4 acc[4][4] = {};
    int bb = blockIdx.y;
    int b  = b0 + bb;
    const u16* A = q + (size_t)b * 4096 * 128;
    const u16* B = k + (size_t)b * 4096 * 128;
    int L = xcd_swz(blockIdx.x, 512);
    int m0 = (L % 32) * 128, n0 = (L / 32) * 256;
    gemm_core(A, 128, B, 128, 4, m0, n0, lds, acc);

    u16* Pb = P + (size_t)bb * 4096 * 4096;
    const float sc = 1.f / (128.f * 4096.f);
    EPI_COORDS();
    #pragma unroll
    for (int mi = 0; mi < 4; ++mi)
        #pragma unroll
        for (int nj = 0; nj < 4; ++nj)
            #pragma unroll
            for (int rr = 0; rr < 4; ++rr) {
                int m = m0 + wr * 64 + mi * 16 + lq * 4 + rr;
                int n = n0 + wc * 64 + nj * 16 + lr;
                float a = fmaxf(acc[mi][nj][rr], 0.f);
                Pb[(size_t)m * 4096 + n] = f2bf(a * a * sc);
            }
}

// ---------------------------------------------------------------------------
// PV: z = P @ v (B = vT); epilogue uz = u * z in place over h's u-region.
// Grid (192, 2): 32 m-tiles x 6 n-tiles per batch.
// ---------------------------------------------------------------------------
__global__ __launch_bounds__(512, 4) void k_zu(
    const u16* __restrict__ P, const u16* __restrict__ vT, u16* __restrict__ h, int b0)
{
    __shared__ __align__(16) u16 lds[3 * 12288];
    f32x4 acc[4][4] = {};
    int bb = blockIdx.y;
    int b  = b0 + bb;
    const u16* A = P  + (size_t)bb * 4096 * 4096;   // 4096 x 4096
    const u16* B = vT + (size_t)b * 1536 * 4096;    // 1536 x 4096 (N x K)
    int L = xcd_swz(blockIdx.x, 192);
    int m0 = (L % 32) * 128, n0 = (L / 32) * 256;
    gemm_core(A, 4096, B, 4096, 128, m0, n0, lds, acc);

    EPI_COORDS();
    #pragma unroll
    for (int mi = 0; mi < 4; ++mi)
        #pragma unroll
        for (int nj = 0; nj < 4; ++nj)
            #pragma unroll
            for (int rr = 0; rr < 4; ++rr) {
                int m = m0 + wr * 64 + mi * 16 + lq * 4 + rr;
                int n = n0 + wc * 64 + nj * 16 + lr;
                size_t idx = (size_t)(b * 4096 + m) * 3328 + n;
                h[idx] = f2bf(bf2f(h[idx]) * acc[mi][nj][rr]);
            }
}

// ---------------------------------------------------------------------------
// GEMM3: o = (u*z) @ Wo + bo -> f32 out  (A = h's u-region, lda 3328)
// Grid 384 = 128 m-tiles x 3 n-tiles.
// ---------------------------------------------------------------------------
__global__ __launch_bounds__(512, 4) void k_out(
    const u16* __restrict__ h, const u16* __restrict__ WobT,
    const float* __restrict__ bo, float* __restrict__ out)
{
    __shared__ __align__(16) u16 lds[3 * 12288];
    f32x4 acc[4][4] = {};
    int L = xcd_swz(blockIdx.x, 384);
    int m0 = (L % 128) * 128, n0 = (L / 128) * 256;
    gemm_core(h, 3328, WobT, 1536, 48, m0, n0, lds, acc);

    EPI_COORDS();
    #pragma unroll
    for (int mi = 0; mi < 4; ++mi)
        #pragma unroll
        for (int nj = 0; nj < 4; ++nj)
            #pragma unroll
            for (int rr = 0; rr < 4; ++rr) {
                int m = m0 + wr * 64 + mi * 16 + lq * 4 + rr;
                int n = n0 + wc * 64 + nj * 16 + lr;
                out[(size_t)m * 768 + n] = acc[mi][nj][rr] + bo[n];
            }
}

// ---------------------------------------------------------------------------
extern "C" void kernel_launch(void* const* d_in, const int* in_sizes, int n_in,
                              void* d_out, int out_size, void* d_ws, size_t ws_size,
                              hipStream_t stream)
{
    const float* x  = (const float*)d_in[0];
    const float* Wi = (const float*)d_in[1];
    const float* bi = (const float*)d_in[2];
    const float* gq = (const float*)d_in[3];
    const float* bq = (const float*)d_in[4];
    const float* gk = (const float*)d_in[5];
    const float* bk = (const float*)d_in[6];
    const float* Wo = (const float*)d_in[7];
    const float* bo = (const float*)d_in[8];
    float* out = (float*)d_out;

    char* ws = (char*)d_ws;
    size_t off = 0;
    auto alloc = [&](size_t bytes) -> void* {
        void* p = ws + off;
        off += (bytes + 255) & ~(size_t)255;
        return p;
    };
    u16* xb   = (u16*)alloc((size_t)16384 * 768 * 2);
    u16* WibT = (u16*)alloc((size_t)3328 * 768 * 2);     // padded N: 3200 -> 3328
    u16* WobT = (u16*)alloc((size_t)768 * 1536 * 2);
    u16* h    = (u16*)alloc((size_t)16384 * 3328 * 2);   // raw GEMM1 out; u/uz in place
    u16* vT   = (u16*)alloc((size_t)4 * 1536 * 4096 * 2);
    u16* q    = (u16*)alloc((size_t)16384 * 128 * 2);
    u16* k    = (u16*)alloc((size_t)16384 * 128 * 2);
    u16* P    = (u16*)alloc((size_t)2 * 4096 * 4096 * 2); // 2-batch chunk (ws-safe)

    k_cast_x<<<dim3(12288), dim3(256), 0, stream>>>(x, xb);
    k_transpose_w<<<dim3(3328 / 32, 768 / 32), dim3(32, 8), 0, stream>>>(Wi, WibT, 768, 3200);
    k_transpose_w<<<dim3(768 / 32, 1536 / 32), dim3(32, 8), 0, stream>>>(Wo, WobT, 1536, 768);

    k_gemm1<<<dim3(1664), dim3(512), 0, stream>>>(xb, WibT, h);
    k_split<<<dim3(256, 50), dim3(256), 0, stream>>>(h, bi, gq, bq, gk, bk, vT, q, k);

    for (int b0 = 0; b0 < 4; b0 += 2) {
        k_scores<<<dim3(512, 2), dim3(512), 0, stream>>>(q, k, P, b0);
        k_zu<<<dim3(192, 2), dim3(512), 0, stream>>>(P, vT, h, b0);
    }

    k_out<<<dim3(384), dim3(512), 0, stream>>>(h, WobT, bo, out);
}